// Round 6
// baseline (179.804 us; speedup 1.0000x reference)
//
#include <hip/hip_runtime.h>
#include <hip/hip_bf16.h>

typedef unsigned short ushort_t;
typedef __attribute__((ext_vector_type(8))) short v8s;   // 8 bf16 = 4 VGPR (MFMA A/B)
typedef __attribute__((ext_vector_type(4))) float v4f;   // MFMA C/D

// ---------------------------------------------------------------------------
// ws layout (ushort indices unless noted):
//   pack1 [0, 22528)        conv1 A-frags (weights), dense K: [ks 11][nt 4][lane 64][8]
//   pack2 [22528, 26624)    conv2 A-frags hi|lo-in-j: [nt 4][mt2 2][lane 64][8]
//   pack3 [26624, 47104)    conv3 B-frags (hi only): [ks 40][lane 64][8]
//   floats at us 47104 (float idx 23552):
#define B1F_F   23552      // 64
#define B2F_F   23616      // 32
#define B3F_F   23648      // 4
#define WTAB_F  23652      // 32 (8 phases x 4 taps)
#define FLAG_I  23684      // int (1 = bf16 inputs/outputs, 0 = fp32)
#define PK1_US  0
#define PK2_US  22528
#define PK3_US  26624
#define UP_US   48256      // bf16 NHWC [16][256][256][4]  (4M us = 8 MB)
#define H2_US   4242560    // bf16 NHWC [16][256][256][32] (32M us = 64 MB)
#define CVT_TOTAL (47104 + 132)
// ---------------------------------------------------------------------------

__device__ __forceinline__ ushort_t f2us(float v) {
  __hip_bfloat16 h = __float2bfloat16(v);
  return *reinterpret_cast<ushort_t*>(&h);
}
__device__ __forceinline__ float us2f(unsigned int u) { return __uint_as_float(u << 16); }

// RNE-pack two finite floats into two bf16 (lo = a, hi = b).
__device__ __forceinline__ unsigned int bfpair(float a, float b) {
  unsigned int ua = __float_as_uint(a), ub = __float_as_uint(b);
  ua += 0x7fffu + ((ua >> 16) & 1u);
  ub += 0x7fffu + ((ub >> 16) & 1u);
  return (ua >> 16) | (ub & 0xffff0000u);
}

__device__ __forceinline__ float load_in(const void* p, int i, int isbf16) {
  if (isbf16) return us2f(((const unsigned short*)p)[i]);
  return ((const float*)p)[i];
}
__device__ __forceinline__ float4 load_in4(const void* p, int i4, int isbf16) {
  if (isbf16) {
    unsigned long long q = *(const unsigned long long*)((const unsigned short*)p + i4);
    return make_float4(us2f((unsigned int)(q & 0xffff)),
                       us2f((unsigned int)((q >> 16) & 0xffff)),
                       us2f((unsigned int)((q >> 32) & 0xffff)),
                       us2f((unsigned int)((q >> 48) & 0xffff)));
  }
  return *(const float4*)((const float*)p + i4);
}

__device__ __forceinline__ float cubicw(float d) {
  const float Ac = -0.75f;
  d = fabsf(d);
  float d2 = d * d, d3 = d2 * d;
  if (d <= 1.f) return (Ac + 2.f) * d3 - (Ac + 3.f) * d2 + 1.f;
  if (d < 2.f)  return Ac * d3 - 5.f * Ac * d2 + 8.f * Ac * d - 4.f * Ac;
  return 0.f;
}

// ---------------- K_cvt: inline dtype probe + build weight packs -----------
__global__ __launch_bounds__(256) void k_cvt(
    const void* __restrict__ x,
    const void* __restrict__ w1, const void* __restrict__ b1,
    const void* __restrict__ w2, const void* __restrict__ b2,
    const void* __restrict__ w3, const void* __restrict__ b3,
    ushort_t* __restrict__ wsus, float* __restrict__ wsf,
    int* __restrict__ flag) {
  __shared__ int scnt;
  const int tid = threadIdx.x;
  if (tid == 0) scnt = 0;
  __syncthreads();
  {
    const unsigned short* xr = (const unsigned short*)x;
    int c = 0;
    for (int s = tid; s < 512; s += 256) {
      unsigned short h = xr[2 * s];
      int e = (h >> 7) & 0xFF;
      if (e >= 110 && e <= 135) c++;
    }
    if (c) atomicAdd(&scnt, c);
  }
  __syncthreads();
  const int f = (scnt >= 256) ? 1 : 0;
  if (blockIdx.x == 0 && tid == 0) flag[0] = f;

  int i = blockIdx.x * 256 + tid;
  if (i >= CVT_TOTAL) return;
  if (i < 22528) {
    // pack1 dense: k = ks*32+quad*8+j; k<324: tap=k>>2 (ky=tap/9,kx=tap%9), ic=k&3
    int j  = i & 7;
    int l  = (i >> 3) & 63;
    int nt = (i >> 9) & 3;
    int ks = i >> 11;
    int k  = ks * 32 + ((l >> 4) & 3) * 8 + j;
    int oc = nt * 16 + (l & 15);
    float v = 0.f;
    if (k < 324) {
      int tap = k >> 2, ic = k & 3;
      int ky = tap / 9, kx = tap - ky * 9;
      v = load_in(w1, ((oc * 4 + ic) * 9 + ky) * 9 + kx, f);
    }
    wsus[PK1_US + i] = f2us(v);
    return;
  }
  if (i < 26624) {
    // pack2: [nt][mt2][lane][8]; j<4 = hi(w2), j>=4 = lo residual
    int t = i - 22528;
    int j   = t & 7;
    int l   = (t >> 3) & 63;
    int mt2 = (t >> 9) & 1;
    int nt  = (t >> 10) & 3;
    int oc1 = nt * 16 + ((l >> 4) & 3) * 4 + (j & 3);
    int oc2 = mt2 * 16 + (l & 15);
    float w = load_in(w2, oc2 * 64 + oc1, f);
    float hi = us2f(f2us(w));
    wsus[PK2_US + t] = (j < 4) ? f2us(w) : f2us(w - hi);
    return;
  }
  if (i < 47104) {
    // pack3 (hi only): [ks 40][lane][8]; k=ky*256+jj*32+ic; n=dx*4+oc
    int t = i - 26624;
    int j8 = t & 7;
    int l  = (t >> 3) & 63;
    int ks = t >> 9;
    int k  = ks * 32 + ((l >> 4) & 3) * 8 + j8;
    int n  = l & 15;
    int ky = k >> 8, jj = (k >> 5) & 7, ic = k & 31;
    int dx = n >> 2, oc = n & 3;
    int kx = jj - dx;
    float w = 0.f;
    if (kx >= 0 && kx <= 4)
      w = load_in(w3, ((oc * 32 + ic) * 5 + ky) * 5 + kx, f);
    wsus[PK3_US + t] = f2us(w);
    return;
  }
  int t = i - 47104;
  if (t < 64) { wsf[B1F_F + t] = load_in(b1, t, f); return; }
  if (t < 96) { wsf[B2F_F + (t - 64)] = load_in(b2, t - 64, f); return; }
  if (t < 100) { wsf[B3F_F + (t - 96)] = load_in(b3, t - 96, f); return; }
  if (t < 132) {
    int p = (t - 100) >> 2, a = (t - 100) & 3;
    float frac = (p + 0.5f) * 0.125f - 0.5f;
    float fl = floorf(frac);
    float tt = frac - fl;
    wsf[WTAB_F + (t - 100)] = cubicw(tt - (float)(a - 1));
  }
}

// ---------------- K1: bicubic x8 upscale -> bf16 NHWC ----------------------
__global__ __launch_bounds__(256) void k_upscale(
    const void* __restrict__ x, ushort_t* __restrict__ up,
    const float* __restrict__ wsf, const int* __restrict__ flag) {
  const int f = flag[0];
  int n = blockIdx.x * 256 + threadIdx.x;
  int xo = n & 255, yo = (n >> 8) & 255, b = n >> 16;
  int px = xo & 7, py = yo & 7;
  const float* wt = wsf + WTAB_F;
  float4 wx = *(const float4*)(wt + px * 4);
  float4 wy = *(const float4*)(wt + py * 4);
  float wya[4] = {wy.x, wy.y, wy.z, wy.w};
  int bx = (xo >> 3) + ((px >= 4) ? 0 : -1);
  int by = (yo >> 3) + ((py >= 4) ? 0 : -1);
  int ix0 = min(max(bx - 1, 0), 31), ix1 = min(max(bx, 0), 31);
  int ix2 = min(max(bx + 1, 0), 31), ix3 = min(max(bx + 2, 0), 31);
  float ax = 0.f, ay = 0.f, az = 0.f, aw = 0.f;
#pragma unroll
  for (int a = 0; a < 4; a++) {
    int iy = min(max(by + a - 1, 0), 31);
    int rowb = (b * 32 + iy) * 32;
    float4 p0 = load_in4(x, (rowb + ix0) * 4, f);
    float4 p1 = load_in4(x, (rowb + ix1) * 4, f);
    float4 p2 = load_in4(x, (rowb + ix2) * 4, f);
    float4 p3 = load_in4(x, (rowb + ix3) * 4, f);
    float rx = wx.x * p0.x + wx.y * p1.x + wx.z * p2.x + wx.w * p3.x;
    float ry = wx.x * p0.y + wx.y * p1.y + wx.z * p2.y + wx.w * p3.y;
    float rz = wx.x * p0.z + wx.y * p1.z + wx.z * p2.z + wx.w * p3.z;
    float rw = wx.x * p0.w + wx.y * p1.w + wx.z * p2.w + wx.w * p3.w;
    ax = fmaf(wya[a], rx, ax); ay = fmaf(wya[a], ry, ay);
    az = fmaf(wya[a], rz, az); aw = fmaf(wya[a], rw, aw);
  }
  unsigned long long q =
      (unsigned long long)bfpair(ax, ay) |
      ((unsigned long long)bfpair(az, aw) << 32);
  *(unsigned long long*)(up + n * 4) = q;
}

// ---------------- K2: MFMA conv9x9(4->64)+ReLU -> MFMA conv1x1(64->32)+ReLU
// 512 thr = 8 waves; wave w owns 2 mtiles (py=w, pxh=0/16) -> acc = 32 AGPRs
// (halved vs r5) so 4 waves/SIMD fit.  w2 frags loaded at epilogue (post
// K-loop register pressure).  conv1 D (oc rows, pixel cols) feeds conv2
// directly as B-operand; hi|lo w2 split folded into j.
__global__ __launch_bounds__(512, 4) void k_conv12(
    const ushort_t* __restrict__ up, const ushort_t* __restrict__ wsus,
    const float* __restrict__ wsf, ushort_t* __restrict__ h2) {
  __shared__ __align__(16) ushort_t patchA[16 * 48 * 4];  // [y][x][4ic] 12288 B
  const int b  = blockIdx.z;
  const int x0 = blockIdx.x * 32, y0 = blockIdx.y * 8;
  const int tid = threadIdx.x;

  // stage 16x48 positions from bf16 NHWC up (zero pad)
#pragma unroll
  for (int i = 0; i < 2; ++i) {
    int e = tid + i * 512;                  // 0..1023, guard 768
    if (e < 768) {
      int yy = e / 48, xx = e % 48;
      int gy = y0 + yy - 4, gx = x0 + xx - 4;
      unsigned long long q = 0ull;
      if (gy >= 0 && gy < 256 && gx >= 0 && gx < 256)
        q = *(const unsigned long long*)(up + (((b * 256 + gy) * 256 + gx) << 2));
      *(unsigned long long*)(patchA + e * 4) = q;
    }
  }
  __syncthreads();

  const int lane = tid & 63, wave = tid >> 6;   // wave 0..7 = py
  const int quad = lane >> 4, lc = lane & 15;
  int base_m[2], pix0_[2];
#pragma unroll
  for (int i = 0; i < 2; ++i) {
    base_m[i] = (wave * 48 + i * 16 + lc) << 2;  // ushort idx of (py=wave, pxh+lc, ic0)
    pix0_[i] = wave * 32 + i * 16;
  }
  v4f acc[2][4];
#pragma unroll
  for (int i = 0; i < 2; ++i)
#pragma unroll
    for (int nt = 0; nt < 4; ++nt) acc[i][nt] = (v4f){0.f, 0.f, 0.f, 0.f};

  const v8s* __restrict__ Ap1 = (const v8s*)(wsus + PK1_US);
  for (int ks = 0; ks < 11; ++ks) {
    v8s Af[4];
#pragma unroll
    for (int nt = 0; nt < 4; ++nt) Af[nt] = Ap1[(ks * 4 + nt) * 64 + lane];
    int tap0 = ks * 8 + quad * 2;
    int tap1 = min(tap0 + 1, 80);
    tap0 = min(tap0, 80);
    int ky0 = tap0 / 9, kx0 = tap0 - ky0 * 9;
    int ky1 = tap1 / 9, kx1 = tap1 - ky1 * 9;
    int off0 = (ky0 * 48 + kx0) << 2;
    int off1 = (ky1 * 48 + kx1) << 2;
#pragma unroll
    for (int i = 0; i < 2; ++i) {
      union { unsigned long long q[2]; v8s v; } u;
      u.q[0] = *(const unsigned long long*)(patchA + base_m[i] + off0);
      u.q[1] = *(const unsigned long long*)(patchA + base_m[i] + off1);
#pragma unroll
      for (int nt = 0; nt < 4; ++nt)
        acc[i][nt] = __builtin_amdgcn_mfma_f32_16x16x32_bf16(Af[nt], u.v, acc[i][nt], 0, 0, 0);
    }
  }

  // epilogue: +b1, ReLU, pack -> conv2 MFMA -> +b2, ReLU, packed h2 store
  v8s w2f[4][2];
#pragma unroll
  for (int nt = 0; nt < 4; ++nt)
#pragma unroll
    for (int mt2 = 0; mt2 < 2; ++mt2)
      w2f[nt][mt2] = ((const v8s*)(wsus + PK2_US))[(nt * 2 + mt2) * 64 + lane];
  float4 b1q[4];
#pragma unroll
  for (int nt = 0; nt < 4; ++nt)
    b1q[nt] = *(const float4*)(wsf + B1F_F + nt * 16 + quad * 4);
  float4 b2q[2];
#pragma unroll
  for (int mt2 = 0; mt2 < 2; ++mt2)
    b2q[mt2] = *(const float4*)(wsf + B2F_F + mt2 * 16 + quad * 4);

#pragma unroll
  for (int i = 0; i < 2; ++i) {
    v4f a2[2];
    a2[0] = (v4f){0.f, 0.f, 0.f, 0.f};
    a2[1] = (v4f){0.f, 0.f, 0.f, 0.f};
#pragma unroll
    for (int nt = 0; nt < 4; ++nt) {
      float r0 = fmaxf(acc[i][nt][0] + b1q[nt].x, 0.f);
      float r1 = fmaxf(acc[i][nt][1] + b1q[nt].y, 0.f);
      float r2 = fmaxf(acc[i][nt][2] + b1q[nt].z, 0.f);
      float r3 = fmaxf(acc[i][nt][3] + b1q[nt].w, 0.f);
      unsigned int u0 = bfpair(r0, r1), u1 = bfpair(r2, r3);
      union { unsigned int q[4]; v8s v; } bu;
      bu.q[0] = u0; bu.q[1] = u1; bu.q[2] = u0; bu.q[3] = u1;
#pragma unroll
      for (int mt2 = 0; mt2 < 2; ++mt2)
        a2[mt2] = __builtin_amdgcn_mfma_f32_16x16x32_bf16(w2f[nt][mt2], bu.v, a2[mt2], 0, 0, 0);
    }
    int pix = pix0_[i] + lc;
    int gy = y0 + (pix >> 5), gx = x0 + (pix & 31);
    ushort_t* dst = h2 + (((b * 256 + gy) * 256 + gx) << 5) + (quad << 2);
#pragma unroll
    for (int mt2 = 0; mt2 < 2; ++mt2) {
      float v0 = fmaxf(a2[mt2][0] + b2q[mt2].x, 0.f);
      float v1 = fmaxf(a2[mt2][1] + b2q[mt2].y, 0.f);
      float v2 = fmaxf(a2[mt2][2] + b2q[mt2].z, 0.f);
      float v3 = fmaxf(a2[mt2][3] + b2q[mt2].w, 0.f);
      unsigned long long q =
          (unsigned long long)bfpair(v0, v1) |
          ((unsigned long long)bfpair(v2, v3) << 32);
      *(unsigned long long*)(dst + mt2 * 16) = q;
    }
  }
}

// ---------------- K3: MFMA conv5x5(32->4) via dx-in-N trick ----------------
// n=(dx 0..3, oc 0..3); k=(ky 0..4, j=dx+kx 0..7, ic 0..31), K=1280, 40 ksteps.
// tile 32x16 px, grid (8,16,16); M=128 (8 q-tiles), wave owns 2 q.
__global__ __launch_bounds__(256) void k_conv3(
    const ushort_t* __restrict__ h2, const ushort_t* __restrict__ wsus,
    const float* __restrict__ wsf, void* __restrict__ out,
    const int* __restrict__ flag) {
  __shared__ __align__(16) ushort_t patch[20 * 1160];  // [y 20][x 36][ic 32] + 8 pad/row
  const int b  = blockIdx.z;
  const int x0 = blockIdx.x * 32, y0 = blockIdx.y * 16;
  const int tid = threadIdx.x;

  for (int e = tid; e < 720; e += 256) {
    int yy = e / 36, xx = e - yy * 36;
    int gy = y0 + yy - 2, gx = x0 + xx - 2;
    ushort_t* dst = patch + yy * 1160 + xx * 32;
    if (gy >= 0 && gy < 256 && gx >= 0 && gx < 256) {
      const ushort_t* src = h2 + (((b * 256 + gy) * 256 + gx) << 5);
#pragma unroll
      for (int c = 0; c < 4; ++c)
        *(float4*)(dst + c * 8) = *(const float4*)(src + c * 8);
    } else {
      float4 z = make_float4(0.f, 0.f, 0.f, 0.f);
#pragma unroll
      for (int c = 0; c < 4; ++c) *(float4*)(dst + c * 8) = z;
    }
  }
  __syncthreads();

  const int lane = tid & 63, wave = tid >> 6;
  const int quad = lane >> 4, lc = lane & 15;
  v4f acc[2];
  acc[0] = (v4f){0.f, 0.f, 0.f, 0.f};
  acc[1] = (v4f){0.f, 0.f, 0.f, 0.f};
  const v8s* __restrict__ Bp3 = (const v8s*)(wsus + PK3_US);

  for (int ks = 0; ks < 40; ++ks) {
    v8s Bh = Bp3[ks * 64 + lane];
    int ky = ks >> 3, j = ks & 7;
    int rowoff = (lc + ky) * 1160 + j * 32 + quad * 8;
#pragma unroll
    for (int i = 0; i < 2; ++i) {
      int q = wave * 2 + i;
      v8s Af = *(const v8s*)(patch + rowoff + q * 128);
      acc[i] = __builtin_amdgcn_mfma_f32_16x16x32_bf16(Af, Bh, acc[i], 0, 0, 0);
    }
  }

  // epilogue: C/D row=quad*4+r -> y_local, col=lc -> (dx=lc>>2, oc=lc&3)
  float b3v = (wsf + B3F_F)[lc & 3];
  const int fl = flag[0];
#pragma unroll
  for (int i = 0; i < 2; ++i) {
    int q = wave * 2 + i;
#pragma unroll
    for (int r = 0; r < 4; ++r) {
      int gy = y0 + (quad << 2) + r;
      int gx = x0 + (q << 2) + (lc >> 2);
      int idx = (((b * 256 + gy) * 256 + gx) << 2) + (lc & 3);
      float vv = acc[i][r] + b3v;
      if (fl) ((ushort_t*)out)[idx] = f2us(vv);
      else    ((float*)out)[idx] = vv;
    }
  }
}

// ---------------------------------------------------------------------------
extern "C" void kernel_launch(void* const* d_in, const int* in_sizes, int n_in,
                              void* d_out, int out_size, void* d_ws, size_t ws_size,
                              hipStream_t stream) {
  const void* x  = d_in[0];
  const void* w1 = d_in[1];
  const void* b1 = d_in[2];
  const void* w2 = d_in[3];
  const void* b2 = d_in[4];
  const void* w3 = d_in[5];
  const void* b3 = d_in[6];

  ushort_t* wsus = (ushort_t*)d_ws;
  float* wsf = (float*)d_ws;
  int* flag = (int*)((float*)d_ws + FLAG_I);
  ushort_t* up = wsus + UP_US;
  ushort_t* h2 = wsus + H2_US;

  k_cvt<<<(CVT_TOTAL + 255) / 256, 256, 0, stream>>>(x, w1, b1, w2, b2, w3, b3,
                                                     wsus, wsf, flag);
  k_upscale<<<4096, 256, 0, stream>>>(x, up, wsf, flag);
  k_conv12<<<dim3(8, 32, 16), 512, 0, stream>>>(up, wsus, wsf, h2);
  k_conv3<<<dim3(8, 16, 16), 256, 0, stream>>>(h2, wsus, wsf, d_out, flag);
}

// Round 7
// 161.405 us; speedup vs baseline: 1.1140x; 1.1140x over previous
//
#include <hip/hip_runtime.h>
#include <hip/hip_bf16.h>

typedef unsigned short ushort_t;
typedef __attribute__((ext_vector_type(8))) short v8s;   // 8 bf16 = 4 VGPR (MFMA A/B)
typedef __attribute__((ext_vector_type(4))) float v4f;   // MFMA C/D

// ---------------------------------------------------------------------------
// ws layout (ushort indices unless noted):
//   pack1 [0, 22528)        conv1 A-frags (weights), dense K: [ks 11][nt 4][lane 64][8]
//   pack2 [22528, 26624)    conv2 A-frags hi|lo-in-j: [nt 4][mt2 2][lane 64][8]
//   pack3 [26624, 47104)    conv3 B-frags (hi only): [ks 40][lane 64][8]
//   floats at us 47104 (float idx 23552):
#define B1F_F   23552      // 64
#define B2F_F   23616      // 32
#define B3F_F   23648      // 4
#define WTAB_F  23652      // 32 (8 phases x 4 taps)
#define FLAG_I  23684      // int (1 = bf16 inputs/outputs, 0 = fp32)
#define PK1_US  0
#define PK2_US  22528
#define PK3_US  26624
#define UP_US   48256      // bf16 NHWC [16][256][256][4]  (4M us = 8 MB)
#define H2_US   4242560    // bf16 NHWC [16][256][256][32] (32M us = 64 MB)
#define CVT_TOTAL (47104 + 132)
// ---------------------------------------------------------------------------

__device__ __forceinline__ ushort_t f2us(float v) {
  __hip_bfloat16 h = __float2bfloat16(v);
  return *reinterpret_cast<ushort_t*>(&h);
}
__device__ __forceinline__ float us2f(unsigned int u) { return __uint_as_float(u << 16); }

// RNE-pack two finite floats into two bf16 (lo = a, hi = b).
__device__ __forceinline__ unsigned int bfpair(float a, float b) {
  unsigned int ua = __float_as_uint(a), ub = __float_as_uint(b);
  ua += 0x7fffu + ((ua >> 16) & 1u);
  ub += 0x7fffu + ((ub >> 16) & 1u);
  return (ua >> 16) | (ub & 0xffff0000u);
}

__device__ __forceinline__ float load_in(const void* p, int i, int isbf16) {
  if (isbf16) return us2f(((const unsigned short*)p)[i]);
  return ((const float*)p)[i];
}
__device__ __forceinline__ float4 load_in4(const void* p, int i4, int isbf16) {
  if (isbf16) {
    unsigned long long q = *(const unsigned long long*)((const unsigned short*)p + i4);
    return make_float4(us2f((unsigned int)(q & 0xffff)),
                       us2f((unsigned int)((q >> 16) & 0xffff)),
                       us2f((unsigned int)((q >> 32) & 0xffff)),
                       us2f((unsigned int)((q >> 48) & 0xffff)));
  }
  return *(const float4*)((const float*)p + i4);
}

__device__ __forceinline__ float cubicw(float d) {
  const float Ac = -0.75f;
  d = fabsf(d);
  float d2 = d * d, d3 = d2 * d;
  if (d <= 1.f) return (Ac + 2.f) * d3 - (Ac + 3.f) * d2 + 1.f;
  if (d < 2.f)  return Ac * d3 - 5.f * Ac * d2 + 8.f * Ac * d - 4.f * Ac;
  return 0.f;
}

// ---------------- K_cvt: inline dtype probe + build weight packs -----------
__global__ __launch_bounds__(256) void k_cvt(
    const void* __restrict__ x,
    const void* __restrict__ w1, const void* __restrict__ b1,
    const void* __restrict__ w2, const void* __restrict__ b2,
    const void* __restrict__ w3, const void* __restrict__ b3,
    ushort_t* __restrict__ wsus, float* __restrict__ wsf,
    int* __restrict__ flag) {
  __shared__ int scnt;
  const int tid = threadIdx.x;
  if (tid == 0) scnt = 0;
  __syncthreads();
  {
    const unsigned short* xr = (const unsigned short*)x;
    int c = 0;
    for (int s = tid; s < 512; s += 256) {
      unsigned short h = xr[2 * s];
      int e = (h >> 7) & 0xFF;
      if (e >= 110 && e <= 135) c++;
    }
    if (c) atomicAdd(&scnt, c);
  }
  __syncthreads();
  const int f = (scnt >= 256) ? 1 : 0;
  if (blockIdx.x == 0 && tid == 0) flag[0] = f;

  int i = blockIdx.x * 256 + tid;
  if (i >= CVT_TOTAL) return;
  if (i < 22528) {
    // pack1 dense: k = ks*32+quad*8+j; k<324: tap=k>>2 (ky=tap/9,kx=tap%9), ic=k&3
    int j  = i & 7;
    int l  = (i >> 3) & 63;
    int nt = (i >> 9) & 3;
    int ks = i >> 11;
    int k  = ks * 32 + ((l >> 4) & 3) * 8 + j;
    int oc = nt * 16 + (l & 15);
    float v = 0.f;
    if (k < 324) {
      int tap = k >> 2, ic = k & 3;
      int ky = tap / 9, kx = tap - ky * 9;
      v = load_in(w1, ((oc * 4 + ic) * 9 + ky) * 9 + kx, f);
    }
    wsus[PK1_US + i] = f2us(v);
    return;
  }
  if (i < 26624) {
    // pack2: [nt][mt2][lane][8]; j<4 = hi(w2), j>=4 = lo residual
    int t = i - 22528;
    int j   = t & 7;
    int l   = (t >> 3) & 63;
    int mt2 = (t >> 9) & 1;
    int nt  = (t >> 10) & 3;
    int oc1 = nt * 16 + ((l >> 4) & 3) * 4 + (j & 3);
    int oc2 = mt2 * 16 + (l & 15);
    float w = load_in(w2, oc2 * 64 + oc1, f);
    float hi = us2f(f2us(w));
    wsus[PK2_US + t] = (j < 4) ? f2us(w) : f2us(w - hi);
    return;
  }
  if (i < 47104) {
    // pack3 (hi only): [ks 40][lane][8]; k=ky*256+jj*32+ic; n=dx*4+oc
    int t = i - 26624;
    int j8 = t & 7;
    int l  = (t >> 3) & 63;
    int ks = t >> 9;
    int k  = ks * 32 + ((l >> 4) & 3) * 8 + j8;
    int n  = l & 15;
    int ky = k >> 8, jj = (k >> 5) & 7, ic = k & 31;
    int dx = n >> 2, oc = n & 3;
    int kx = jj - dx;
    float w = 0.f;
    if (kx >= 0 && kx <= 4)
      w = load_in(w3, ((oc * 32 + ic) * 5 + ky) * 5 + kx, f);
    wsus[PK3_US + t] = f2us(w);
    return;
  }
  int t = i - 47104;
  if (t < 64) { wsf[B1F_F + t] = load_in(b1, t, f); return; }
  if (t < 96) { wsf[B2F_F + (t - 64)] = load_in(b2, t - 64, f); return; }
  if (t < 100) { wsf[B3F_F + (t - 96)] = load_in(b3, t - 96, f); return; }
  if (t < 132) {
    int p = (t - 100) >> 2, a = (t - 100) & 3;
    float frac = (p + 0.5f) * 0.125f - 0.5f;
    float fl = floorf(frac);
    float tt = frac - fl;
    wsf[WTAB_F + (t - 100)] = cubicw(tt - (float)(a - 1));
  }
}

// ---------------- K1: bicubic x8 upscale -> bf16 NHWC ----------------------
__global__ __launch_bounds__(256) void k_upscale(
    const void* __restrict__ x, ushort_t* __restrict__ up,
    const float* __restrict__ wsf, const int* __restrict__ flag) {
  const int f = flag[0];
  int n = blockIdx.x * 256 + threadIdx.x;
  int xo = n & 255, yo = (n >> 8) & 255, b = n >> 16;
  int px = xo & 7, py = yo & 7;
  const float* wt = wsf + WTAB_F;
  float4 wx = *(const float4*)(wt + px * 4);
  float4 wy = *(const float4*)(wt + py * 4);
  float wya[4] = {wy.x, wy.y, wy.z, wy.w};
  int bx = (xo >> 3) + ((px >= 4) ? 0 : -1);
  int by = (yo >> 3) + ((py >= 4) ? 0 : -1);
  int ix0 = min(max(bx - 1, 0), 31), ix1 = min(max(bx, 0), 31);
  int ix2 = min(max(bx + 1, 0), 31), ix3 = min(max(bx + 2, 0), 31);
  float ax = 0.f, ay = 0.f, az = 0.f, aw = 0.f;
#pragma unroll
  for (int a = 0; a < 4; a++) {
    int iy = min(max(by + a - 1, 0), 31);
    int rowb = (b * 32 + iy) * 32;
    float4 p0 = load_in4(x, (rowb + ix0) * 4, f);
    float4 p1 = load_in4(x, (rowb + ix1) * 4, f);
    float4 p2 = load_in4(x, (rowb + ix2) * 4, f);
    float4 p3 = load_in4(x, (rowb + ix3) * 4, f);
    float rx = wx.x * p0.x + wx.y * p1.x + wx.z * p2.x + wx.w * p3.x;
    float ry = wx.x * p0.y + wx.y * p1.y + wx.z * p2.y + wx.w * p3.y;
    float rz = wx.x * p0.z + wx.y * p1.z + wx.z * p2.z + wx.w * p3.z;
    float rw = wx.x * p0.w + wx.y * p1.w + wx.z * p2.w + wx.w * p3.w;
    ax = fmaf(wya[a], rx, ax); ay = fmaf(wya[a], ry, ay);
    az = fmaf(wya[a], rz, az); aw = fmaf(wya[a], rw, aw);
  }
  unsigned long long q =
      (unsigned long long)bfpair(ax, ay) |
      ((unsigned long long)bfpair(az, aw) << 32);
  *(unsigned long long*)(up + n * 4) = q;
}

// ---------------- K2: MFMA conv9x9(4->64)+ReLU -> MFMA conv1x1(64->32)+ReLU
// 256 thr = 4 waves; wave owns 4 mtiles (r5 shape, best FLOP/A-byte).
// conv1 weight frags (pack1, 45 KB) staged ONCE per block into LDS: kills the
// per-wave L2 re-fetch that bounded r5/r6.  LDS total 51200 B -> 3 blocks/CU.
__global__ __launch_bounds__(256, 3) void k_conv12(
    const ushort_t* __restrict__ up, const ushort_t* __restrict__ wsus,
    const float* __restrict__ wsf, ushort_t* __restrict__ h2) {
  __shared__ __align__(16) ushort_t patchA[16 * 48 * 4];  // 6144 B
  __shared__ __align__(16) ushort_t pack1L[22528];        // 45056 B
  const int b  = blockIdx.z;
  const int x0 = blockIdx.x * 32, y0 = blockIdx.y * 8;
  const int tid = threadIdx.x;

  // stage 16x48 patch positions from bf16 NHWC up (zero pad)
#pragma unroll
  for (int i = 0; i < 3; ++i) {
    int e = tid + i * 256;                  // 0..767
    int yy = e / 48, xx = e % 48;
    int gy = y0 + yy - 4, gx = x0 + xx - 4;
    unsigned long long q = 0ull;
    if (gy >= 0 && gy < 256 && gx >= 0 && gx < 256)
      q = *(const unsigned long long*)(up + (((b * 256 + gy) * 256 + gx) << 2));
    *(unsigned long long*)(patchA + e * 4) = q;
  }
  // stage pack1 -> LDS (2816 x 16B, 11 per thread)
  {
    const v8s* src = (const v8s*)(wsus + PK1_US);
    v8s* dst = (v8s*)pack1L;
#pragma unroll
    for (int i = 0; i < 11; ++i) {
      int e = tid + i * 256;
      dst[e] = src[e];
    }
  }
  __syncthreads();

  const int lane = tid & 63, wave = tid >> 6;
  const int quad = lane >> 4, lc = lane & 15;
  int base_m[4], pix0_[4];
#pragma unroll
  for (int i = 0; i < 4; ++i) {
    int mt = wave * 4 + i;
    int py = mt >> 1, pxh = (mt & 1) << 4;
    base_m[i] = (py * 48 + pxh + lc) << 2;   // ushort idx of (py, pxh+lc, ic0)
    pix0_[i] = py * 32 + pxh;
  }
  v4f acc[4][4];
#pragma unroll
  for (int i = 0; i < 4; ++i)
#pragma unroll
    for (int nt = 0; nt < 4; ++nt) acc[i][nt] = (v4f){0.f, 0.f, 0.f, 0.f};

  const v8s* __restrict__ Ap1 = (const v8s*)pack1L;
  for (int ks = 0; ks < 11; ++ks) {
    v8s Af[4];
#pragma unroll
    for (int nt = 0; nt < 4; ++nt) Af[nt] = Ap1[(ks * 4 + nt) * 64 + lane];
    int tap0 = ks * 8 + quad * 2;
    int tap1 = min(tap0 + 1, 80);
    tap0 = min(tap0, 80);
    int ky0 = tap0 / 9, kx0 = tap0 - ky0 * 9;
    int ky1 = tap1 / 9, kx1 = tap1 - ky1 * 9;
    int off0 = (ky0 * 48 + kx0) << 2;
    int off1 = (ky1 * 48 + kx1) << 2;
#pragma unroll
    for (int i = 0; i < 4; ++i) {
      union { unsigned long long q[2]; v8s v; } u;
      u.q[0] = *(const unsigned long long*)(patchA + base_m[i] + off0);
      u.q[1] = *(const unsigned long long*)(patchA + base_m[i] + off1);
#pragma unroll
      for (int nt = 0; nt < 4; ++nt)
        acc[i][nt] = __builtin_amdgcn_mfma_f32_16x16x32_bf16(Af[nt], u.v, acc[i][nt], 0, 0, 0);
    }
  }

  // epilogue: +b1, ReLU, pack -> conv2 MFMA -> +b2, ReLU, packed h2 store
  v8s w2f[4][2];
#pragma unroll
  for (int nt = 0; nt < 4; ++nt)
#pragma unroll
    for (int mt2 = 0; mt2 < 2; ++mt2)
      w2f[nt][mt2] = ((const v8s*)(wsus + PK2_US))[(nt * 2 + mt2) * 64 + lane];
  float4 b1q[4];
#pragma unroll
  for (int nt = 0; nt < 4; ++nt)
    b1q[nt] = *(const float4*)(wsf + B1F_F + nt * 16 + quad * 4);
  float4 b2q[2];
#pragma unroll
  for (int mt2 = 0; mt2 < 2; ++mt2)
    b2q[mt2] = *(const float4*)(wsf + B2F_F + mt2 * 16 + quad * 4);

#pragma unroll
  for (int i = 0; i < 4; ++i) {
    v4f a2[2];
    a2[0] = (v4f){0.f, 0.f, 0.f, 0.f};
    a2[1] = (v4f){0.f, 0.f, 0.f, 0.f};
#pragma unroll
    for (int nt = 0; nt < 4; ++nt) {
      float r0 = fmaxf(acc[i][nt][0] + b1q[nt].x, 0.f);
      float r1 = fmaxf(acc[i][nt][1] + b1q[nt].y, 0.f);
      float r2 = fmaxf(acc[i][nt][2] + b1q[nt].z, 0.f);
      float r3 = fmaxf(acc[i][nt][3] + b1q[nt].w, 0.f);
      unsigned int u0 = bfpair(r0, r1), u1 = bfpair(r2, r3);
      union { unsigned int q[4]; v8s v; } bu;
      bu.q[0] = u0; bu.q[1] = u1; bu.q[2] = u0; bu.q[3] = u1;
#pragma unroll
      for (int mt2 = 0; mt2 < 2; ++mt2)
        a2[mt2] = __builtin_amdgcn_mfma_f32_16x16x32_bf16(w2f[nt][mt2], bu.v, a2[mt2], 0, 0, 0);
    }
    int pix = pix0_[i] + lc;
    int gy = y0 + (pix >> 5), gx = x0 + (pix & 31);
    ushort_t* dst = h2 + (((b * 256 + gy) * 256 + gx) << 5) + (quad << 2);
#pragma unroll
    for (int mt2 = 0; mt2 < 2; ++mt2) {
      float v0 = fmaxf(a2[mt2][0] + b2q[mt2].x, 0.f);
      float v1 = fmaxf(a2[mt2][1] + b2q[mt2].y, 0.f);
      float v2 = fmaxf(a2[mt2][2] + b2q[mt2].z, 0.f);
      float v3 = fmaxf(a2[mt2][3] + b2q[mt2].w, 0.f);
      unsigned long long q =
          (unsigned long long)bfpair(v0, v1) |
          ((unsigned long long)bfpair(v2, v3) << 32);
      *(unsigned long long*)(dst + mt2 * 16) = q;
    }
  }
}

// ---------------- K3: MFMA conv5x5(32->4) via dx-in-N trick ----------------
// Weights (40 B-frags = 160 VGPR) preloaded to registers before the K-loop:
// K-loop is pure 2x ds_read_b128 + 2x MFMA per kstep (no per-kstep L2 loads).
__global__ __launch_bounds__(256, 2) void k_conv3(
    const ushort_t* __restrict__ h2, const ushort_t* __restrict__ wsus,
    const float* __restrict__ wsf, void* __restrict__ out,
    const int* __restrict__ flag) {
  __shared__ __align__(16) ushort_t patch[20 * 1160];  // [y 20][x 36][ic 32] + 8 pad/row
  const int b  = blockIdx.z;
  const int x0 = blockIdx.x * 32, y0 = blockIdx.y * 16;
  const int tid = threadIdx.x;

  for (int e = tid; e < 720; e += 256) {
    int yy = e / 36, xx = e - yy * 36;
    int gy = y0 + yy - 2, gx = x0 + xx - 2;
    ushort_t* dst = patch + yy * 1160 + xx * 32;
    if (gy >= 0 && gy < 256 && gx >= 0 && gx < 256) {
      const ushort_t* src = h2 + (((b * 256 + gy) * 256 + gx) << 5);
#pragma unroll
      for (int c = 0; c < 4; ++c)
        *(float4*)(dst + c * 8) = *(const float4*)(src + c * 8);
    } else {
      float4 z = make_float4(0.f, 0.f, 0.f, 0.f);
#pragma unroll
      for (int c = 0; c < 4; ++c) *(float4*)(dst + c * 8) = z;
    }
  }

  const int lane = tid & 63, wave = tid >> 6;
  const int quad = lane >> 4, lc = lane & 15;

  // preload ALL conv3 weight frags into registers (40 x v8s = 160 VGPR)
  v8s Wf[40];
  {
    const v8s* __restrict__ Bp3 = (const v8s*)(wsus + PK3_US);
#pragma unroll
    for (int ks = 0; ks < 40; ++ks) Wf[ks] = Bp3[ks * 64 + lane];
  }
  __syncthreads();

  v4f acc[2];
  acc[0] = (v4f){0.f, 0.f, 0.f, 0.f};
  acc[1] = (v4f){0.f, 0.f, 0.f, 0.f};

#pragma unroll
  for (int ks = 0; ks < 40; ++ks) {
    int ky = ks >> 3, j = ks & 7;
    int rowoff = (lc + ky) * 1160 + j * 32 + quad * 8;
#pragma unroll
    for (int i = 0; i < 2; ++i) {
      int q = wave * 2 + i;
      v8s Af = *(const v8s*)(patch + rowoff + q * 128);
      acc[i] = __builtin_amdgcn_mfma_f32_16x16x32_bf16(Af, Wf[ks], acc[i], 0, 0, 0);
    }
  }

  // epilogue: C/D row=quad*4+r -> y_local, col=lc -> (dx=lc>>2, oc=lc&3)
  float b3v = (wsf + B3F_F)[lc & 3];
  const int fl = flag[0];
#pragma unroll
  for (int i = 0; i < 2; ++i) {
    int q = wave * 2 + i;
#pragma unroll
    for (int r = 0; r < 4; ++r) {
      int gy = y0 + (quad << 2) + r;
      int gx = x0 + (q << 2) + (lc >> 2);
      int idx = (((b * 256 + gy) * 256 + gx) << 2) + (lc & 3);
      float vv = acc[i][r] + b3v;
      if (fl) ((ushort_t*)out)[idx] = f2us(vv);
      else    ((float*)out)[idx] = vv;
    }
  }
}

// ---------------------------------------------------------------------------
extern "C" void kernel_launch(void* const* d_in, const int* in_sizes, int n_in,
                              void* d_out, int out_size, void* d_ws, size_t ws_size,
                              hipStream_t stream) {
  const void* x  = d_in[0];
  const void* w1 = d_in[1];
  const void* b1 = d_in[2];
  const void* w2 = d_in[3];
  const void* b2 = d_in[4];
  const void* w3 = d_in[5];
  const void* b3 = d_in[6];

  ushort_t* wsus = (ushort_t*)d_ws;
  float* wsf = (float*)d_ws;
  int* flag = (int*)((float*)d_ws + FLAG_I);
  ushort_t* up = wsus + UP_US;
  ushort_t* h2 = wsus + H2_US;

  k_cvt<<<(CVT_TOTAL + 255) / 256, 256, 0, stream>>>(x, w1, b1, w2, b2, w3, b3,
                                                     wsus, wsf, flag);
  k_upscale<<<4096, 256, 0, stream>>>(x, up, wsf, flag);
  k_conv12<<<dim3(8, 32, 16), 256, 0, stream>>>(up, wsus, wsf, h2);
  k_conv3<<<dim3(8, 16, 16), 256, 0, stream>>>(h2, wsus, wsf, d_out, flag);
}